// Round 1
// baseline (459.677 us; speedup 1.0000x reference)
//
#include <hip/hip_runtime.h>
#include <hip/hip_bf16.h>
#include <cstdint>

typedef _Float16 half_t;
typedef _Float16 f16x8 __attribute__((ext_vector_type(8), aligned(16)));
typedef _Float16 f16x4 __attribute__((ext_vector_type(4), aligned(8)));
typedef _Float16 f16x2 __attribute__((ext_vector_type(2), aligned(4)));
typedef float f32x4 __attribute__((ext_vector_type(4)));

#define B_ 128
#define C_ 2048
#define N_ 196
#define S_ 312
#define L_ 300
#define M_ 1024
#define NP 224   // padded N (14 x 16)
#define SP 384   // padded S for prep GEMMs (3 x 128)

// ---- async global->LDS, 16B per lane ----
__device__ __forceinline__ void gload16(const half_t* g, half_t* l) {
    __builtin_amdgcn_global_load_lds((const __attribute__((address_space(1))) void*)g,
                                     (__attribute__((address_space(3))) void*)l, 16, 0, 0);
}

// ---------------------------------------------------------------------------
// K0: q[s][m] = sum_l att[s][l]*Wq[m][l] + bq[m]   -> fp16 [384][1024], zero pad
// grid (16 mc, 48 sc), block 256
__global__ __launch_bounds__(256) void k_q(const float* __restrict__ att, const float* __restrict__ Wq,
                                           const float* __restrict__ bq, half_t* __restrict__ qh) {
    int mc = blockIdx.x, sc = blockIdx.y;
    int s0 = sc * 8;
    __shared__ float als[8][L_];
    int t = threadIdx.x;
    for (int idx = t; idx < 8 * L_; idx += 256) {
        int si = idx / L_, li = idx % L_;
        als[si][li] = (s0 + si < S_) ? att[(size_t)(s0 + si) * L_ + li] : 0.f;
    }
    __syncthreads();
    int wid = t >> 6, lane = t & 63;
    for (int mi = 0; mi < 16; ++mi) {
        int m = mc * 64 + wid * 16 + mi;
        float acc[8] = {0, 0, 0, 0, 0, 0, 0, 0};
        for (int r = 0; r < 5; ++r) {
            int li = lane + 64 * r;
            if (li < L_) {
                float wv = Wq[(size_t)m * L_ + li];
#pragma unroll
                for (int k = 0; k < 8; ++k) acc[k] += als[k][li] * wv;
            }
        }
#pragma unroll
        for (int k = 0; k < 8; ++k) {
            float v = acc[k];
            for (int off = 32; off; off >>= 1) v += __shfl_xor(v, off);
            if (lane == 0) {
                int s = s0 + k;
                float res = (s < S_) ? (v + bq[m]) : 0.f;
                qh[(size_t)s * M_ + m] = (half_t)res;
            }
        }
    }
}

// ---------------------------------------------------------------------------
// generic transpose+convert: in [R][Cc] f32 -> out [Cc][R] f16. R,Cc multiples of 64.
// grid (Cc/64, R/64), block 256
__global__ __launch_bounds__(256) void k_transp(const float* __restrict__ in, half_t* __restrict__ out,
                                                int R, int Cc) {
    __shared__ __attribute__((aligned(16))) half_t lsT[64][72];
    int c0 = blockIdx.x * 64, r0 = blockIdx.y * 64;
    int t = threadIdx.x;
#pragma unroll
    for (int i = 0; i < 4; ++i) {
        int Q = t + 256 * i;
        int rq = Q >> 5, cq = Q & 31;
        int rr = 2 * rq, cc = 2 * cq;
        const float* p0 = in + (size_t)(r0 + rr) * Cc + c0 + cc;
        float2 va = *(const float2*)p0;
        float2 vb = *(const float2*)(p0 + Cc);
        f16x2 w0; w0[0] = (half_t)va.x; w0[1] = (half_t)vb.x;
        f16x2 w1; w1[0] = (half_t)va.y; w1[1] = (half_t)vb.y;
        *(f16x2*)&lsT[cc][rr]     = w0;   // lsT[c][r] = in[r][c]
        *(f16x2*)&lsT[cc + 1][rr] = w1;
    }
    __syncthreads();
    int cl = t >> 2, ch = t & 3;
    f16x8 v0 = *(const f16x8*)&lsT[cl][ch * 16];
    f16x8 v1 = *(const f16x8*)&lsT[cl][ch * 16 + 8];
    half_t* po = out + (size_t)(c0 + cl) * R + r0 + ch * 16;
    *(f16x8*)po = v0;
    *(f16x8*)(po + 8) = v1;
}

// ---------------------------------------------------------------------------
// V_final f32 [312][2048] -> f16 [384][2048] zero-padded. grid 768, block 256
__global__ __launch_bounds__(256) void k_vconv(const float* __restrict__ V, half_t* __restrict__ Vh) {
    size_t e = ((size_t)blockIdx.x * 256 + threadIdx.x) * 4;
    int s = (int)(e / C_), c = (int)(e % C_);
    float4 v = {0, 0, 0, 0};
    if (s < S_) v = *(const float4*)&V[(size_t)s * C_ + c];
    f16x4 h; h[0] = (half_t)v.x; h[1] = (half_t)v.y; h[2] = (half_t)v.z; h[3] = (half_t)v.w;
    *(f16x4*)&Vh[e] = h;
}

// ---------------------------------------------------------------------------
// m97-style fp16 GEMM: C[r][col] = sum_k A[r][k] * Bm[col][k]
// A: [gridDim.y*128][kdim], Bm: [gridDim.x*128][kdim], both f16 row-major.
// MODE 0: outF (f32) all rows.  MODE 1: outH (f16), rows < 320 only.
// MODE 2: outF (f32) + outH (f16), all rows.
template <int MODE>
__global__ __launch_bounds__(256) void k_gemm(const half_t* __restrict__ A, const half_t* __restrict__ Bm,
                                              int kdim, float* __restrict__ outF, half_t* __restrict__ outH,
                                              int ldo) {
    __shared__ __attribute__((aligned(16))) half_t lsA[128 * 32];
    __shared__ __attribute__((aligned(16))) half_t lsB[128 * 32];
    int t = threadIdx.x;
    int wid = t >> 6, lane = t & 63;
    int tN = blockIdx.x, tM = blockIdx.y;
    const int rA0 = tM * 128, rB0 = tN * 128;
    int wr = wid >> 1, wc = wid & 1;
    int g = lane >> 4, l15 = lane & 15;
    f32x4 acc[4][4] = {};
    for (int kc = 0; kc < kdim; kc += 32) {
#pragma unroll
        for (int q = 0; q < 2; ++q) {
            int li = q * 256 + t;
            int r = li >> 2, kk = (li & 3) * 8;
            gload16(A + (size_t)(rA0 + r) * kdim + kc + kk, &lsA[li * 8]);
            gload16(Bm + (size_t)(rB0 + r) * kdim + kc + kk, &lsB[li * 8]);
        }
        __syncthreads();
        f16x8 af[4], bf[4];
#pragma unroll
        for (int i = 0; i < 4; ++i) af[i] = *(const f16x8*)&lsA[(wr * 64 + i * 16 + l15) * 32 + g * 8];
#pragma unroll
        for (int j = 0; j < 4; ++j) bf[j] = *(const f16x8*)&lsB[(wc * 64 + j * 16 + l15) * 32 + g * 8];
#pragma unroll
        for (int i = 0; i < 4; ++i)
#pragma unroll
            for (int j = 0; j < 4; ++j)
                acc[i][j] = __builtin_amdgcn_mfma_f32_16x16x32_f16(af[i], bf[j], acc[i][j], 0, 0, 0);
        __syncthreads();
    }
#pragma unroll
    for (int i = 0; i < 4; ++i) {
        int r0 = rA0 + wr * 64 + i * 16 + (lane >> 4) * 4;
#pragma unroll
        for (int j = 0; j < 4; ++j) {
            int c0 = rB0 + wc * 64 + j * 16 + l15;
#pragma unroll
            for (int qq = 0; qq < 4; ++qq) {
                int r = r0 + qq;
                if (MODE == 0) {
                    outF[(size_t)r * ldo + c0] = acc[i][j][qq];
                } else if (MODE == 1) {
                    if (r < 320) outH[(size_t)r * ldo + c0] = (half_t)acc[i][j][qq];
                } else {
                    outF[(size_t)r * ldo + c0] = acc[i][j][qq];
                    outH[(size_t)r * ldo + c0] = (half_t)acc[i][j][qq];
                }
            }
        }
    }
}

// ---------------------------------------------------------------------------
// feat [nB][2048][196] f32 -> featT [(bb*224 + n)][2048] f16, n padded to 224 w/ zeros
// grid (4 nT, 32 cT, nB), block 256
__global__ __launch_bounds__(256) void k_transf(const float* __restrict__ feat, half_t* __restrict__ featT) {
    __shared__ __attribute__((aligned(16))) half_t lsT[64][72];
    int nT = blockIdx.x, cT = blockIdx.y, bb = blockIdx.z;
    int n0 = nT * 64, c0 = cT * 64;
    const float* fb = feat + (size_t)bb * C_ * N_;
    int t = threadIdx.x;
#pragma unroll
    for (int i = 0; i < 4; ++i) {
        int Q = t + 256 * i;
        int cq = Q >> 5, nq = Q & 31;
        int cc = 2 * cq, nn = 2 * nq;
        int n = n0 + nn;
        float2 va = {0, 0}, vb = {0, 0};
        if (n < N_) {  // n even -> n+1 <= 195 also valid
            const float* p0 = fb + (size_t)(c0 + cc) * N_ + n;
            va = *(const float2*)p0;
            vb = *(const float2*)(p0 + N_);
        }
        f16x2 w0; w0[0] = (half_t)va.x; w0[1] = (half_t)vb.x;
        f16x2 w1; w1[0] = (half_t)va.y; w1[1] = (half_t)vb.y;
        *(f16x2*)&lsT[nn][cc]     = w0;   // lsT[n][c]
        *(f16x2*)&lsT[nn + 1][cc] = w1;
    }
    __syncthreads();
    int nl = t >> 2, ch = t & 3;
    int n = n0 + nl;
    if (n < NP) {
        f16x8 v0 = *(const f16x8*)&lsT[nl][ch * 16];
        f16x8 v1 = *(const f16x8*)&lsT[nl][ch * 16 + 8];
        half_t* po = featT + ((size_t)bb * NP + n) * C_ + c0 + ch * 16;
        *(f16x8*)po = v0;
        *(f16x8*)(po + 8) = v1;
    }
}

// ---------------------------------------------------------------------------
// pool[b][c] = mean_n feat[b][c][n].  grid 128*32, block 256 (4 waves x 16 rows)
__global__ __launch_bounds__(256) void k_pool(const float* __restrict__ feat, float* __restrict__ pool) {
    int bx = blockIdx.x;
    int b = bx >> 5, cc = bx & 31;
    int t = threadIdx.x, wid = t >> 6, lane = t & 63;
    for (int r = 0; r < 16; ++r) {
        int c = cc * 64 + wid * 16 + r;
        const float* p = feat + ((size_t)b * C_ + c) * N_;
        float s = p[lane] + p[lane + 64] + p[lane + 128];
        if (lane < 4) s += p[lane + 192];
        for (int off = 32; off; off >>= 1) s += __shfl_xor(s, off);
        if (lane == 0) pool[(size_t)b * C_ + c] = s * (1.0f / 196.0f);
    }
}

// ---------------------------------------------------------------------------
// base[b][s] = sum_c (pool[b][c] + bo[c]) * V[s][c].  grid (4 sc, 128 b), block 256
__global__ __launch_bounds__(256) void k_poolv(const float* __restrict__ pool, const float* __restrict__ bo,
                                               const float* __restrict__ V, float* __restrict__ base) {
    int sc = blockIdx.x, b = blockIdx.y;
    __shared__ float w[C_];
    int t = threadIdx.x;
    for (int i = t; i < C_; i += 256) w[i] = pool[(size_t)b * C_ + i] + bo[i];
    __syncthreads();
    int wid = t >> 6, lane = t & 63;
    for (int s = sc * 78 + wid; s < sc * 78 + 78; s += 4) {
        const float* vr = V + (size_t)s * C_;
        float acc = 0;
#pragma unroll
        for (int i = 0; i < 32; ++i) acc += w[lane + 64 * i] * vr[lane + 64 * i];
        for (int off = 32; off; off >>= 1) acc += __shfl_xor(acc, off);
        if (lane == 0) base[(size_t)b * S_ + s] = acc;
    }
}

// ---------------------------------------------------------------------------
// ubv[s] = sum_m U[s][m]*bv[m].  grid 78, block 256 (wave per s)
__global__ __launch_bounds__(256) void k_ubv(const float* __restrict__ U, const float* __restrict__ bv,
                                             float* __restrict__ ubv) {
    int s = blockIdx.x * 4 + (threadIdx.x >> 6);
    int lane = threadIdx.x & 63;
    if (s >= S_) return;
    const float* ur = U + (size_t)s * M_;
    float acc = 0;
#pragma unroll
    for (int i = 0; i < 16; ++i) acc += ur[lane + 64 * i] * bv[lane + 64 * i];
    for (int off = 32; off; off >>= 1) acc += __shfl_xor(acc, off);
    if (lane == 0) ubv[s] = acc;
}

// ---------------------------------------------------------------------------
// softmax over n + dot: out[b][s] = base + ubv + sum_n softmax(scores)_n * W2_n
// Cm rows 0..311 = scores, rows 320..631 = W2; cols = bb*224 + n
// grid nB*78, block 256 (wave per (bb,s))
__global__ __launch_bounds__(256) void k_reduce(const float* __restrict__ Cm, int ncols,
                                                const float* __restrict__ base, const float* __restrict__ ubv,
                                                float* __restrict__ out, int b0) {
    int w = blockIdx.x * 4 + (threadIdx.x >> 6);
    int lane = threadIdx.x & 63;
    int bb = w / S_, s = w % S_;
    const float* rs = Cm + (size_t)s * ncols + bb * NP;
    const float* rw = Cm + (size_t)(320 + s) * ncols + bb * NP;
    f32x4 sv = {0, 0, 0, 0}, wv = {0, 0, 0, 0};
    int j0 = lane * 4;
    if (j0 < N_) {
        sv = *(const f32x4*)(rs + j0);
        wv = *(const f32x4*)(rw + j0);
    }
    float m = -3.0e38f;
#pragma unroll
    for (int e = 0; e < 4; ++e)
        if (j0 + e < N_) m = fmaxf(m, sv[e]);
    for (int off = 32; off; off >>= 1) m = fmaxf(m, __shfl_xor(m, off));
    float ls = 0, dot = 0;
#pragma unroll
    for (int e = 0; e < 4; ++e) {
        if (j0 + e < N_) {
            float p = __expf(sv[e] - m);
            ls += p;
            dot += p * wv[e];
        }
    }
    for (int off = 32; off; off >>= 1) {
        ls += __shfl_xor(ls, off);
        dot += __shfl_xor(dot, off);
    }
    if (lane == 0) {
        int bg = b0 + bb;
        out[(size_t)bg * S_ + s] = base[(size_t)bg * S_ + s] + ubv[s] + dot / ls;
    }
}

// ---------------------------------------------------------------------------
extern "C" void kernel_launch(void* const* d_in, const int* in_sizes, int n_in,
                              void* d_out, int out_size, void* d_ws, size_t ws_size,
                              hipStream_t stream) {
    const float* feat = (const float*)d_in[0];
    const float* att  = (const float*)d_in[1];
    const float* Wq   = (const float*)d_in[2];
    const float* bq   = (const float*)d_in[3];
    const float* Wk   = (const float*)d_in[4];
    /* bk = d_in[5] — adds a per-s constant to scores over n: softmax-invariant, dropped */
    const float* Wv   = (const float*)d_in[6];
    const float* bv   = (const float*)d_in[7];
    const float* Wo   = (const float*)d_in[8];
    const float* bo   = (const float*)d_in[9];
    const float* V    = (const float*)d_in[10];
    float* out = (float*)d_out;

    auto AL = [](size_t x) { return (x + 255) & ~(size_t)255; };
    const size_t szAstack = (size_t)640 * 2048 * 2;
    const size_t szQh = (size_t)SP * M_ * 2;
    const size_t szVh = (size_t)SP * C_ * 2;
    const size_t szUf = (size_t)SP * M_ * 4;
    const size_t szUh = (size_t)SP * M_ * 2;
    const size_t szWT = (size_t)2048 * 1024 * 2;  // each of WkT/WoT/WvT
    const size_t szPool = (size_t)B_ * C_ * 4;
    const size_t szBase = (size_t)B_ * S_ * 4;
    const size_t szUbv = (size_t)S_ * 4;
    size_t fixed = AL(szAstack) + AL(szQh) + AL(szVh) + AL(szUf) + AL(szUh) + 3 * AL(szWT) +
                   AL(szPool) + AL(szBase) + AL(szUbv);

    int nsplit = 1;
    while (nsplit < 32) {
        size_t nB = B_ / nsplit;
        size_t need = fixed + AL(nB * NP * C_ * 2) + AL((size_t)640 * nB * NP * 4);
        if (need <= ws_size) break;
        nsplit *= 2;
    }
    int nB = B_ / nsplit;

    char* p = (char*)d_ws;
    half_t* Astack = (half_t*)p; p += AL(szAstack);
    half_t* qh     = (half_t*)p; p += AL(szQh);
    half_t* Vh     = (half_t*)p; p += AL(szVh);
    float*  Uf     = (float*)p;  p += AL(szUf);
    half_t* Uh     = (half_t*)p; p += AL(szUh);
    half_t* WkT    = (half_t*)p; p += AL(szWT);
    half_t* WoT    = (half_t*)p; p += AL(szWT);
    half_t* WvT    = (half_t*)p; p += AL(szWT);
    float*  pool   = (float*)p;  p += AL(szPool);
    float*  base   = (float*)p;  p += AL(szBase);
    float*  ubv    = (float*)p;  p += AL(szUbv);
    half_t* featT  = (half_t*)p; p += AL((size_t)nB * NP * C_ * 2);
    float*  Cbuf   = (float*)p;

    // ---- batch-independent precompute ----
    k_q<<<dim3(16, 48), 256, 0, stream>>>(att, Wq, bq, qh);
    k_transp<<<dim3(32, 16), 256, 0, stream>>>(Wk, WkT, 1024, 2048);   // WkT[c][m]
    // Qk = q @ Wk  -> Astack rows 0..319 (f16), pads zero
    k_gemm<1><<<dim3(16, 3), 256, 0, stream>>>(qh, WkT, 1024, nullptr, Astack, 2048);
    k_vconv<<<dim3(768), 256, 0, stream>>>(V, Vh);
    k_transp<<<dim3(16, 32), 256, 0, stream>>>(Wo, WoT, 2048, 1024);   // WoT[m][c]
    // U = V @ Wo  -> Uf (f32) + Uh (f16)
    k_gemm<2><<<dim3(8, 3), 256, 0, stream>>>(Vh, WoT, 2048, Uf, Uh, 1024);
    k_ubv<<<dim3(78), 256, 0, stream>>>(Uf, bv, ubv);
    k_transp<<<dim3(32, 16), 256, 0, stream>>>(Wv, WvT, 1024, 2048);   // WvT[c][m]
    // Wv2 = U @ Wv -> Astack rows 320..639 (f16)
    k_gemm<1><<<dim3(16, 3), 256, 0, stream>>>(Uh, WvT, 1024, nullptr, Astack + (size_t)320 * 2048, 2048);

    // ---- pooling path ----
    k_pool<<<dim3(B_ * 32), 256, 0, stream>>>(feat, pool);
    k_poolv<<<dim3(4, B_), 256, 0, stream>>>(pool, bo, V, base);

    // ---- main per-batch-split pipeline ----
    for (int h = 0; h < nsplit; ++h) {
        const float* fh = feat + (size_t)h * nB * C_ * N_;
        k_transf<<<dim3(4, 32, nB), 256, 0, stream>>>(fh, featT);
        int ncols = nB * NP;
        k_gemm<0><<<dim3(ncols / 128, 5), 256, 0, stream>>>(Astack, featT, 2048, Cbuf, nullptr, ncols);
        k_reduce<<<dim3(nB * 78), 256, 0, stream>>>(Cbuf, ncols, base, ubv, out, h * nB);
    }
}

// Round 2
// 351.426 us; speedup vs baseline: 1.3080x; 1.3080x over previous
//
#include <hip/hip_runtime.h>
#include <hip/hip_bf16.h>
#include <cstdint>

typedef _Float16 half_t;
typedef _Float16 f16x8 __attribute__((ext_vector_type(8), aligned(16)));
typedef _Float16 f16x4 __attribute__((ext_vector_type(4), aligned(8)));
typedef _Float16 f16x2 __attribute__((ext_vector_type(2), aligned(4)));
typedef float f32x4 __attribute__((ext_vector_type(4)));

#define B_ 128
#define C_ 2048
#define N_ 196
#define S_ 312
#define L_ 300
#define LP 320   // padded L (10 x 32)
#define M_ 1024
#define NP 224   // padded N (14 x 16)
#define SP 384   // padded S for prep GEMMs (3 x 128)

// ---- async global->LDS, 16B per lane ----
__device__ __forceinline__ void gload16(const half_t* g, half_t* l) {
    __builtin_amdgcn_global_load_lds((const __attribute__((address_space(1))) void*)g,
                                     (__attribute__((address_space(3))) void*)l, 16, 0, 0);
}

// ---------------------------------------------------------------------------
// One-shot f32->f16 pad/convert for att [312,300]->[384,320], Wq [1024,300]->[1024,320],
// V_final [312,2048]->[384,2048].  grid (768,1,3), block 256
__global__ __launch_bounds__(256) void k_convert(const float* __restrict__ att, const float* __restrict__ Wq,
                                                 const float* __restrict__ V, half_t* __restrict__ atth,
                                                 half_t* __restrict__ wqh, half_t* __restrict__ vh) {
    int z = blockIdx.z;
    size_t e = ((size_t)blockIdx.x * 256 + threadIdx.x) * 4;
    if (z == 0) {
        if (e >= (size_t)SP * LP) return;
        int r = (int)(e / LP), c = (int)(e % LP);
        f16x4 h;
#pragma unroll
        for (int j = 0; j < 4; ++j) h[j] = (half_t)((r < S_ && c + j < L_) ? att[(size_t)r * L_ + c + j] : 0.f);
        *(f16x4*)&atth[e] = h;
    } else if (z == 1) {
        if (e >= (size_t)M_ * LP) return;
        int r = (int)(e / LP), c = (int)(e % LP);
        f16x4 h;
#pragma unroll
        for (int j = 0; j < 4; ++j) h[j] = (half_t)((c + j < L_) ? Wq[(size_t)r * L_ + c + j] : 0.f);
        *(f16x4*)&wqh[e] = h;
    } else {
        if (e >= (size_t)SP * C_) return;
        int r = (int)(e / C_);
        f16x4 h;
        if (r < S_) {
            float4 v = *(const float4*)&V[e];
            h[0] = (half_t)v.x; h[1] = (half_t)v.y; h[2] = (half_t)v.z; h[3] = (half_t)v.w;
        } else {
            h[0] = h[1] = h[2] = h[3] = (half_t)0.f;
        }
        *(f16x4*)&vh[e] = h;
    }
}

// ---------------------------------------------------------------------------
// Three transposes (f32 [R][Cc] -> f16 [Cc][R]) in one dispatch.
// z=0: Wk 1024x2048 -> WkT; z=1: Wo 2048x1024 -> WoT; z=2: Wv 1024x2048 -> WvT
// grid (32,32,3), block 256
__global__ __launch_bounds__(256) void k_transp3(const float* __restrict__ Wk, const float* __restrict__ Wo,
                                                 const float* __restrict__ Wv, half_t* __restrict__ WkT,
                                                 half_t* __restrict__ WoT, half_t* __restrict__ WvT) {
    __shared__ __attribute__((aligned(16))) half_t lsT[64][72];
    int z = blockIdx.z;
    const float* in; half_t* out; int R, Cc;
    if (z == 0)      { in = Wk; out = WkT; R = 1024; Cc = 2048; }
    else if (z == 1) { in = Wo; out = WoT; R = 2048; Cc = 1024; }
    else             { in = Wv; out = WvT; R = 1024; Cc = 2048; }
    if ((int)blockIdx.x >= Cc / 64 || (int)blockIdx.y >= R / 64) return;
    int c0 = blockIdx.x * 64, r0 = blockIdx.y * 64;
    int t = threadIdx.x;
#pragma unroll
    for (int i = 0; i < 4; ++i) {
        int Q = t + 256 * i;
        int rq = Q >> 5, cq = Q & 31;
        int rr = 2 * rq, cc = 2 * cq;
        const float* p0 = in + (size_t)(r0 + rr) * Cc + c0 + cc;
        float2 va = *(const float2*)p0;
        float2 vb = *(const float2*)(p0 + Cc);
        f16x2 w0; w0[0] = (half_t)va.x; w0[1] = (half_t)vb.x;
        f16x2 w1; w1[0] = (half_t)va.y; w1[1] = (half_t)vb.y;
        *(f16x2*)&lsT[cc][rr]     = w0;   // lsT[c][r] = in[r][c]
        *(f16x2*)&lsT[cc + 1][rr] = w1;
    }
    __syncthreads();
    int cl = t >> 2, ch = t & 3;
    f16x8 v0 = *(const f16x8*)&lsT[cl][ch * 16];
    f16x8 v1 = *(const f16x8*)&lsT[cl][ch * 16 + 8];
    half_t* po = out + (size_t)(c0 + cl) * R + r0 + ch * 16;
    *(f16x8*)po = v0;
    *(f16x8*)(po + 8) = v1;
}

// ---------------------------------------------------------------------------
// 2-phase double-buffered fp16 MFMA GEMM: C[r][col] = sum_k A[r][k] * Bm[col][k]
// A: [gridDim.y*128][kdim], Bm: [gridDim.x*128][kdim], both f16 row-major, kdim % 32 == 0.
// MODE 0: outF (f32) all rows.  MODE 1: outH (f16), rows < 320 only.
// MODE 2: outF + outH, all rows.  MODE 3: outH (f16) with f32 bias[col], all rows.
template <int MODE>
__global__ __launch_bounds__(256) void k_gemm(const half_t* __restrict__ A, const half_t* __restrict__ Bm,
                                              int kdim, float* __restrict__ outF, half_t* __restrict__ outH,
                                              int ldo, const float* __restrict__ bias) {
    __shared__ __attribute__((aligned(16))) half_t lsA[2][128 * 32];
    __shared__ __attribute__((aligned(16))) half_t lsB[2][128 * 32];
    int t = threadIdx.x;
    int wid = t >> 6, lane = t & 63;
    const int rA0 = blockIdx.y * 128, rB0 = blockIdx.x * 128;
    int wr = wid >> 1, wc = wid & 1;
    int g = lane >> 4, l15 = lane & 15;
    const int r_ = t >> 2, kk_ = (t & 3) * 8;
    f32x4 acc[4][4] = {};

#define STAGE(bsel, kc)                                                                   \
    do {                                                                                  \
        _Pragma("unroll") for (int q = 0; q < 2; ++q) {                                   \
            int r = q * 64 + r_;                                                          \
            gload16(A + (size_t)(rA0 + r) * kdim + (kc) + kk_, &lsA[bsel][r * 32 + kk_]); \
            gload16(Bm + (size_t)(rB0 + r) * kdim + (kc) + kk_, &lsB[bsel][r * 32 + kk_]);\
        }                                                                                 \
    } while (0)

    STAGE(0, 0);
    __syncthreads();
    int nk = kdim >> 5;
    int cur = 0;
    for (int tk = 0; tk < nk; ++tk) {
        if (tk + 1 < nk) STAGE(cur ^ 1, (tk + 1) * 32);  // prefetch next tile (issue-early)
        f16x8 af[4], bf[4];
#pragma unroll
        for (int i = 0; i < 4; ++i) af[i] = *(const f16x8*)&lsA[cur][(wr * 64 + i * 16 + l15) * 32 + g * 8];
#pragma unroll
        for (int j = 0; j < 4; ++j) bf[j] = *(const f16x8*)&lsB[cur][(wc * 64 + j * 16 + l15) * 32 + g * 8];
#pragma unroll
        for (int i = 0; i < 4; ++i)
#pragma unroll
            for (int j = 0; j < 4; ++j)
                acc[i][j] = __builtin_amdgcn_mfma_f32_16x16x32_f16(af[i], bf[j], acc[i][j], 0, 0, 0);
        __syncthreads();  // drains vmcnt(0) (prefetch landed) + all reads of cur done
        cur ^= 1;
    }
#undef STAGE

#pragma unroll
    for (int i = 0; i < 4; ++i) {
        int r0 = rA0 + wr * 64 + i * 16 + g * 4;
#pragma unroll
        for (int j = 0; j < 4; ++j) {
            int c0 = rB0 + wc * 64 + j * 16 + l15;
            float bval = (MODE == 3) ? bias[c0] : 0.f;
#pragma unroll
            for (int qq = 0; qq < 4; ++qq) {
                int r = r0 + qq;
                float val = acc[i][j][qq];
                if (MODE == 0) {
                    outF[(size_t)r * ldo + c0] = val;
                } else if (MODE == 1) {
                    if (r < 320) outH[(size_t)r * ldo + c0] = (half_t)val;
                } else if (MODE == 2) {
                    outF[(size_t)r * ldo + c0] = val;
                    outH[(size_t)r * ldo + c0] = (half_t)val;
                } else {
                    outH[(size_t)r * ldo + c0] = (half_t)(val + bval);
                }
            }
        }
    }
}

// ---------------------------------------------------------------------------
// feat [nB][2048][196] f32 -> featT [(bb*224 + n)][2048] f16 (n zero-padded to 224)
// PLUS fused pool partials: poolp[(nT*B_ + bb)*C_ + c] = sum over this block's n of feat[b][c][n]
// grid (4 nT, 32 cT, nB), block 256
__global__ __launch_bounds__(256) void k_transf(const float* __restrict__ feat, half_t* __restrict__ featT,
                                                float* __restrict__ poolp) {
    __shared__ __attribute__((aligned(16))) half_t lsT[64][72];
    __shared__ float poolLs[64];
    int nT = blockIdx.x, cT = blockIdx.y, bb = blockIdx.z;
    int n0 = nT * 64, c0 = cT * 64;
    const float* fb = feat + (size_t)bb * C_ * N_;
    int t = threadIdx.x;
#pragma unroll
    for (int i = 0; i < 4; ++i) {
        int Q = t + 256 * i;
        int cq = Q >> 5, nq = Q & 31;
        int cc = 2 * cq, nn = 2 * nq;
        int n = n0 + nn;
        float2 va = {0, 0}, vb = {0, 0};
        if (n < N_) {  // n even -> n+1 <= 195 also valid
            const float* p0 = fb + (size_t)(c0 + cc) * N_ + n;
            va = *(const float2*)p0;
            vb = *(const float2*)(p0 + N_);
        }
        f16x2 w0; w0[0] = (half_t)va.x; w0[1] = (half_t)vb.x;
        f16x2 w1; w1[0] = (half_t)va.y; w1[1] = (half_t)vb.y;
        *(f16x2*)&lsT[nn][cc]     = w0;   // lsT[n][c]
        *(f16x2*)&lsT[nn + 1][cc] = w1;
        // fused pool partial: reduce the 2 n-values, then across the 32-lane nq-group
        float sA = va.x + va.y, sB = vb.x + vb.y;
        for (int off = 16; off; off >>= 1) { sA += __shfl_xor(sA, off); sB += __shfl_xor(sB, off); }
        if ((t & 31) == 0) { poolLs[cc] = sA; poolLs[cc + 1] = sB; }  // each (i, t>>5) owns a distinct cq
    }
    __syncthreads();
    int nl = t >> 2, ch = t & 3;
    int n = n0 + nl;
    if (n < NP) {
        f16x8 v0 = *(const f16x8*)&lsT[nl][ch * 16];
        f16x8 v1 = *(const f16x8*)&lsT[nl][ch * 16 + 8];
        half_t* po = featT + ((size_t)bb * NP + n) * C_ + c0 + ch * 16;
        *(f16x8*)po = v0;
        *(f16x8*)(po + 8) = v1;
    }
    if (t < 64) poolp[((size_t)nT * B_ + bb) * C_ + c0 + t] = poolLs[t];
}

// ---------------------------------------------------------------------------
// base[b][s] = sum_c (mean_pool[b][c] + bo[c]) * V[s][c], pool from 4 partials.
// grid (4 sc, 128 b), block 256
__global__ __launch_bounds__(256) void k_poolv(const float* __restrict__ poolp, const float* __restrict__ bo,
                                               const float* __restrict__ V, float* __restrict__ base) {
    int sc = blockIdx.x, b = blockIdx.y;
    __shared__ float w[C_];
    int t = threadIdx.x;
    for (int i = t; i < C_; i += 256) {
        float s = poolp[(size_t)b * C_ + i] + poolp[((size_t)B_ + b) * C_ + i] +
                  poolp[((size_t)2 * B_ + b) * C_ + i] + poolp[((size_t)3 * B_ + b) * C_ + i];
        w[i] = s * (1.0f / 196.0f) + bo[i];
    }
    __syncthreads();
    int wid = t >> 6, lane = t & 63;
    for (int s = sc * 78 + wid; s < sc * 78 + 78; s += 4) {
        const float* vr = V + (size_t)s * C_;
        float acc = 0;
#pragma unroll
        for (int i = 0; i < 32; ++i) acc += w[lane + 64 * i] * vr[lane + 64 * i];
        for (int off = 32; off; off >>= 1) acc += __shfl_xor(acc, off);
        if (lane == 0) base[(size_t)b * S_ + s] = acc;
    }
}

// ---------------------------------------------------------------------------
// ubv[s] = sum_m U[s][m]*bv[m].  grid 78, block 256 (wave per s)
__global__ __launch_bounds__(256) void k_ubv(const float* __restrict__ U, const float* __restrict__ bv,
                                             float* __restrict__ ubv) {
    int s = blockIdx.x * 4 + (threadIdx.x >> 6);
    int lane = threadIdx.x & 63;
    if (s >= S_) return;
    const float* ur = U + (size_t)s * M_;
    float acc = 0;
#pragma unroll
    for (int i = 0; i < 16; ++i) acc += ur[lane + 64 * i] * bv[lane + 64 * i];
    for (int off = 32; off; off >>= 1) acc += __shfl_xor(acc, off);
    if (lane == 0) ubv[s] = acc;
}

// ---------------------------------------------------------------------------
// softmax over n + dot: out[b][s] = base + ubv + sum_n softmax(scores)_n * W2_n
// Cm rows 0..311 = scores, rows 320..631 = W2; cols = bb*224 + n
// grid nB*78, block 256 (wave per (bb,s))
__global__ __launch_bounds__(256) void k_reduce(const float* __restrict__ Cm, int ncols,
                                                const float* __restrict__ base, const float* __restrict__ ubv,
                                                float* __restrict__ out, int b0) {
    int w = blockIdx.x * 4 + (threadIdx.x >> 6);
    int lane = threadIdx.x & 63;
    int bb = w / S_, s = w % S_;
    const float* rs = Cm + (size_t)s * ncols + bb * NP;
    const float* rw = Cm + (size_t)(320 + s) * ncols + bb * NP;
    f32x4 sv = {0, 0, 0, 0}, wv = {0, 0, 0, 0};
    int j0 = lane * 4;
    if (j0 < N_) {
        sv = *(const f32x4*)(rs + j0);
        wv = *(const f32x4*)(rw + j0);
    }
    float m = -3.0e38f;
#pragma unroll
    for (int e = 0; e < 4; ++e)
        if (j0 + e < N_) m = fmaxf(m, sv[e]);
    for (int off = 32; off; off >>= 1) m = fmaxf(m, __shfl_xor(m, off));
    float ls = 0, dot = 0;
#pragma unroll
    for (int e = 0; e < 4; ++e) {
        if (j0 + e < N_) {
            float p = __expf(sv[e] - m);
            ls += p;
            dot += p * wv[e];
        }
    }
    for (int off = 32; off; off >>= 1) {
        ls += __shfl_xor(ls, off);
        dot += __shfl_xor(dot, off);
    }
    if (lane == 0) {
        int bg = b0 + bb;
        out[(size_t)bg * S_ + s] = base[(size_t)bg * S_ + s] + ubv[s] + dot / ls;
    }
}

// ---------------------------------------------------------------------------
extern "C" void kernel_launch(void* const* d_in, const int* in_sizes, int n_in,
                              void* d_out, int out_size, void* d_ws, size_t ws_size,
                              hipStream_t stream) {
    const float* feat = (const float*)d_in[0];
    const float* att  = (const float*)d_in[1];
    const float* Wq   = (const float*)d_in[2];
    const float* bq   = (const float*)d_in[3];
    const float* Wk   = (const float*)d_in[4];
    /* bk = d_in[5] — per-s constant over n in scores: softmax-invariant, dropped */
    const float* Wv   = (const float*)d_in[6];
    const float* bv   = (const float*)d_in[7];
    const float* Wo   = (const float*)d_in[8];
    const float* bo   = (const float*)d_in[9];
    const float* V    = (const float*)d_in[10];
    float* out = (float*)d_out;

    auto AL = [](size_t x) { return (x + 255) & ~(size_t)255; };
    const size_t szAstack = (size_t)640 * C_ * 2;
    const size_t szQh   = (size_t)SP * M_ * 2;
    const size_t szVh   = (size_t)SP * C_ * 2;
    const size_t szUf   = (size_t)SP * M_ * 4;
    const size_t szUh   = (size_t)SP * M_ * 2;
    const size_t szWT   = (size_t)C_ * M_ * 2;      // each of WkT/WoT/WvT
    const size_t szAtth = (size_t)SP * LP * 2;
    const size_t szWqh  = (size_t)M_ * LP * 2;
    const size_t szPoolp = (size_t)4 * B_ * C_ * 4;
    const size_t szBase = (size_t)B_ * S_ * 4;
    const size_t szUbv  = (size_t)S_ * 4;
    size_t fixed = AL(szAstack) + AL(szQh) + AL(szVh) + AL(szUf) + AL(szUh) + 3 * AL(szWT) +
                   AL(szAtth) + AL(szWqh) + AL(szPoolp) + AL(szBase) + AL(szUbv);

    int nsplit = 1;
    while (nsplit < 32) {
        size_t nB = B_ / nsplit;
        size_t need = fixed + AL(nB * NP * C_ * 2) + AL((size_t)640 * nB * NP * 4);
        if (need <= ws_size) break;
        nsplit *= 2;
    }
    int nB = B_ / nsplit;

    char* p = (char*)d_ws;
    half_t* Astack = (half_t*)p; p += AL(szAstack);
    half_t* qh     = (half_t*)p; p += AL(szQh);
    half_t* Vh     = (half_t*)p; p += AL(szVh);
    float*  Uf     = (float*)p;  p += AL(szUf);
    half_t* Uh     = (half_t*)p; p += AL(szUh);
    half_t* WkT    = (half_t*)p; p += AL(szWT);
    half_t* WoT    = (half_t*)p; p += AL(szWT);
    half_t* WvT    = (half_t*)p; p += AL(szWT);
    half_t* atth   = (half_t*)p; p += AL(szAtth);
    half_t* wqh    = (half_t*)p; p += AL(szWqh);
    float*  poolp  = (float*)p;  p += AL(szPoolp);
    float*  base   = (float*)p;  p += AL(szBase);
    float*  ubv    = (float*)p;  p += AL(szUbv);
    half_t* featT  = (half_t*)p; p += AL((size_t)nB * NP * C_ * 2);
    float*  Cbuf   = (float*)p;

    // ---- batch-independent precompute ----
    k_convert<<<dim3(768, 1, 3), 256, 0, stream>>>(att, Wq, V, atth, wqh, Vh);
    k_transp3<<<dim3(32, 32, 3), 256, 0, stream>>>(Wk, Wo, Wv, WkT, WoT, WvT);
    // q = att @ Wq.T + bq  (f16, [384][1024])
    k_gemm<3><<<dim3(8, 3), 256, 0, stream>>>(atth, wqh, LP, nullptr, qh, M_, bq);
    // Qk = q @ Wk -> Astack rows 0..319
    k_gemm<1><<<dim3(16, 3), 256, 0, stream>>>(qh, WkT, M_, nullptr, Astack, C_, nullptr);
    // U = V @ Wo -> Uf (f32) + Uh (f16)
    k_gemm<2><<<dim3(8, 3), 256, 0, stream>>>(Vh, WoT, C_, Uf, Uh, M_, nullptr);
    k_ubv<<<dim3(78), 256, 0, stream>>>(Uf, bv, ubv);
    // Wv2 = U @ Wv -> Astack rows 320..639
    k_gemm<1><<<dim3(16, 3), 256, 0, stream>>>(Uh, WvT, M_, nullptr, Astack + (size_t)320 * C_, C_, nullptr);

    // ---- main per-batch-split pipeline ----
    for (int h = 0; h < nsplit; ++h) {
        const float* fh = feat + (size_t)h * nB * C_ * N_;
        k_transf<<<dim3(4, 32, nB), 256, 0, stream>>>(fh, featT, poolp);
        if (h == 0)  // poolp covers full batch only when nsplit==1; recompute base per split
            ;
        k_poolv<<<dim3(4, nB), 256, 0, stream>>>(poolp, bo, V, base + (size_t)h * nB * S_);
        int ncols = nB * NP;
        k_gemm<0><<<dim3(ncols / 128, 5), 256, 0, stream>>>(Astack, featT, C_, Cbuf, nullptr, ncols, nullptr);
        k_reduce<<<dim3(nB * 78), 256, 0, stream>>>(Cbuf, ncols, base, ubv, out, h * nB);
    }
}